// Round 11
// baseline (860.750 us; speedup 1.0000x reference)
//
#include <hip/hip_runtime.h>

#define LL 4096
#define NB 4
#define NC 64
#define NT 4
#define NLAYERS 10
#define XS 5120   // padded x row stride (in l units; x is [B][C][XS][4])
#define XPAD 512  // left/right zero pad (>= max dilation)

typedef float v2f __attribute__((ext_vector_type(2)));

// Constant-address-space cast: forces s_load for wave-uniform weight reads ->
// weights live in SGPRs, FMA is v_fmac_f32 acc, s_w, v_x (proven R6: 47.4us).
typedef __attribute__((address_space(4))) const float cfloat;
__device__ __forceinline__ cfloat* to_constant(const float* p) {
  return (cfloat*)(unsigned long long)p;
}

// ---------------- Threefry-2x32, key = (0, 42), 20 rounds ----------------
__device__ __forceinline__ void threefry2x32(unsigned x0, unsigned x1,
                                             unsigned& o0, unsigned& o1) {
  const unsigned ks0 = 0u, ks1 = 42u;
  const unsigned ks2 = 0x1BD11BDAu ^ ks0 ^ ks1;
  const unsigned ks[3] = {ks0, ks1, ks2};
  const unsigned r0[4] = {13u, 15u, 26u, 6u};
  const unsigned r1[4] = {17u, 29u, 16u, 24u};
  x0 += ks0; x1 += ks1;
#pragma unroll
  for (int g = 0; g < 5; ++g) {
    const unsigned* rr = (g & 1) ? r1 : r0;
#pragma unroll
    for (int j = 0; j < 4; ++j) {
      x0 += x1;
      unsigned r = rr[j];
      x1 = (x1 << r) | (x1 >> (32u - r));
      x1 ^= x0;
    }
    x0 += ks[(g + 1) % 3];
    x1 += ks[(g + 2) % 3] + (unsigned)(g + 1);
  }
  o0 = x0; o1 = x1;
}

__device__ __forceinline__ float u01(unsigned bits) {
  return __uint_as_float((bits >> 9) | 0x3f800000u) - 1.0f;
}

// LIF step: v = v + (x - v)/1.2 ; spike = v>=0.5 ; v *= (1-spike)
__device__ __forceinline__ float lif_step(float& v, float xt) {
  v = v + (xt - v) / 1.2f;
  float s = (v >= 0.5f) ? 1.0f : 0.0f;
  v = v * (1.0f - s);
  return s;
}

// ---------------- prep: transpose skip/res 1x1 + build wT ----------------
// skipT/resT: [i][c'][c]. wT: [i][g16][ci][k][col8], col<4 gate co=g*4+col,
// col>=4 filt co=64+g*4+col-4. (R6 layout.)
__global__ void prep_kernel(const float* __restrict__ skip_w,
                            const float* __restrict__ res_w,
                            const float* __restrict__ conv_w,
                            float* __restrict__ skipT,
                            float* __restrict__ resT,
                            float* __restrict__ wT) {
  int i = blockIdx.x;
  for (int idx = threadIdx.x; idx < 4096; idx += 256) {
    int c = idx >> 6, cp = idx & 63;
    skipT[i * 4096 + cp * 64 + c] = skip_w[i * 4096 + c * 64 + cp];
    resT[i * 4096 + cp * 64 + c] = res_w[i * 4096 + c * 64 + cp];
  }
  for (int idx = threadIdx.x; idx < 16 * 64 * 3 * 8; idx += 256) {
    int col = idx & 7;
    int r = idx >> 3;
    int k = r % 3; r /= 3;
    int ci = r % 64;
    int g = r / 64;  // 0..15
    int co = (col < 4) ? (g * 4 + col) : (64 + g * 4 + (col - 4));
    wT[i * 24576 + idx] = conv_w[(i * 128 + co) * 192 + ci * 3 + k];
  }
}

// ---------------- diffusion embedding + proj + tap sums, ONE kernel --------
// grid 10, block 256. Phase 1 = proj (4b x 64c), phase 2 = pc (512 outputs,
// 2/thread), proj passed via LDS (drops the proj global round-trip and one
// dispatch). Math and summation orders identical to the old proj+pc pair.
__global__ void proj_pc_kernel(const int* __restrict__ dstep,
                               const float* __restrict__ w1, const float* __restrict__ b1,
                               const float* __restrict__ w2, const float* __restrict__ b2,
                               const float* __restrict__ pw, const float* __restrict__ pb,
                               const float* __restrict__ conv_w,
                               float* __restrict__ pc) {
  __shared__ float e1[NB][NC];
  __shared__ float e2[NB][NC];
  __shared__ float pv[NB][NC];
  int i = blockIdx.x;
  int tid = threadIdx.x;
  int b = tid >> 6, c = tid & 63;
  float d = (float)dstep[b];
  float v = d * w1[i * 64 + c] + b1[i * 64 + c];
  v = v / (1.0f + expf(-v));  // silu
  e1[b][c] = v;
  __syncthreads();
  float a = b2[i * 64 + c];
  for (int cp = 0; cp < 64; ++cp) a += e1[b][cp] * w2[(i * 64 + c) * 64 + cp];
  e2[b][c] = a;
  __syncthreads();
  float p = pb[i * 64 + c];
  for (int cp = 0; cp < 64; ++cp) p += e2[b][cp] * pw[(i * 64 + c) * 64 + cp];
  pv[b][c] = p;
  __syncthreads();
  for (int oidx = tid; oidx < 512; oidx += 256) {
    int bb = oidx >> 7;
    int co = oidx & 127;
    const float* w = conv_w + (i * 128 + co) * 192;
    float s0 = 0.0f, s1 = 0.0f, s2 = 0.0f;
    for (int ci = 0; ci < 64; ++ci) {
      float pp = pv[bb][ci];
      s0 += pp * w[ci * 3 + 0];
      s1 += pp * w[ci * 3 + 1];
      s2 += pp * w[ci * 3 + 2];
    }
    float* o = pc + ((i * 4 + bb) * 128 + co) * 3;
    o[0] = s0; o[1] = s1; o[2] = s2;
  }
}

// ---------------- Poisson encode + input conv + LIF -> x [B][C][XS][4] ---------
// Pad-zeroing folded in (padzero dispatch removed): block (lx, b) zeros the
// pad margins of row (b, c=lx) — 256 blocks cover all 256 rows. Pads and
// interior are disjoint addresses; x pads stay zero across layers since
// skip_res only writes the interior.
__global__ void encode_lif_kernel(const float* __restrict__ audio,
                                  const float* __restrict__ W_in,
                                  const float* __restrict__ b_in,
                                  float* __restrict__ x) {
  int tid = threadIdx.x;
  int lq = tid & 63, grp = tid >> 6;
  int l = blockIdx.x * 64 + lq;
  int b = blockIdx.y;
  // zero pads for row (b, c = blockIdx.x)
  {
    float* base = x + (size_t)((b * 64 + blockIdx.x) * XS) * 4;
    for (int q = tid; q < XPAD; q += 256) {
      *(float4*)&base[q * 4] = float4{0.f, 0.f, 0.f, 0.f};
      *(float4*)&base[(XPAD + LL + q) * 4] = float4{0.f, 0.f, 0.f, 0.f};
    }
  }
  float a = audio[b * LL + l];
  unsigned p0 = (unsigned)(b * LL + l);  // t=0 (o0), t=2 (o1)
  unsigned p1 = 16384u + p0;             // t=1 (o0), t=3 (o1)
  unsigned o00, o01, o10, o11;
  threefry2x32(p0, p0 + 32768u, o00, o01);
  threefry2x32(p1, p1 + 32768u, o10, o11);
  float sp[4];
  sp[0] = (u01(o00) < a) ? 1.0f : 0.0f;
  sp[1] = (u01(o10) < a) ? 1.0f : 0.0f;
  sp[2] = (u01(o01) < a) ? 1.0f : 0.0f;
  sp[3] = (u01(o11) < a) ? 1.0f : 0.0f;
  for (int j = 0; j < 16; ++j) {
    int c = grp * 16 + j;
    float w = W_in[c], bb = b_in[c];
    float v = 0.0f;
    float4 o;
    float* op = (float*)&o;
#pragma unroll
    for (int t = 0; t < 4; ++t) op[t] = lif_step(v, w * sp[t] + bb);
    *(float4*)&x[(size_t)((b * 64 + c) * XS + XPAD + l) * 4] = o;
  }
}

// ---------------- dilated conv + LIF + gate -> y [B][64][LL][4] ----------------
// R6 structure (SGPR weights, scalar v_fmac, monotone-pointer x loads) with
// ONE change: x prefetch distance 1 -> 3 phases via ring-4 buffers X[0..3]
// (compile-time slot indices, explicit 2-half body). x is L3-resident
// (21 MB); 1-deep (192cy) covers L1/L2 only, 3-deep (576cy) covers L3
// (~500cy). Weight schedule unchanged. R7's failed attempt differed: it
// pair-clumped loads + recomputed addresses per call; this keeps R6's exact
// load sequence. Accumulation order (ci asc, k asc) -> bit-exact.
template <int DIL>
__global__ __launch_bounds__(256) void layer_conv_kernel(
    const float* __restrict__ x, const float* __restrict__ wT,
    const float* __restrict__ conv_b, const float* __restrict__ pc,
    float* __restrict__ y, int layer) {
  int tid = threadIdx.x;
  int g = blockIdx.y;   // 0..15
  int b = blockIdx.z;
  int l = blockIdx.x * 256 + tid;
  cfloat* cw = to_constant(wT + (size_t)(layer * 16 + g) * 1536);

  const float* px = x + (size_t)(b * 64 * XS + XPAD + l) * 4;  // ci=0 row

  float acc[8][4];  // [col][t]; col 0-3 gate, 4-7 filt
#pragma unroll
  for (int j = 0; j < 8; ++j)
#pragma unroll
    for (int t = 0; t < 4; ++t) acc[j][t] = 0.0f;

  float4 X[4][3];           // ring: slot ci&3, [k] = 4 t values
  float wA[3][8], wB[3][8]; // [k][col] wave-uniform -> SGPRs

  auto loadx = [&](float4* dst) {
    dst[0] = *(const float4*)(px - (size_t)DIL * 4);
    dst[1] = *(const float4*)px;
    dst[2] = *(const float4*)(px + (size_t)DIL * 4);
    px += (size_t)XS * 4;
  };
  auto loadw = [&](int ci, float (*w)[8]) {
#pragma unroll
    for (int k = 0; k < 3; ++k)
#pragma unroll
      for (int j = 0; j < 8; ++j)
        w[k][j] = cw[(ci * 3 + k) * 8 + j];  // s_load (merged)
  };
  auto compute = [&](const float (*w)[8], const float4* xv) {
#pragma unroll
    for (int k = 0; k < 3; ++k) {
      const float* xk = (const float*)&xv[k];
#pragma unroll
      for (int t = 0; t < 4; ++t) {
        float xq = xk[t];
#pragma unroll
        for (int j = 0; j < 8; ++j)
          acc[j][t] += w[k][j] * xq;  // v_fmac_f32 acc, s, v
      }
    }
  };

  loadx(X[0]);  // ci 0
  loadx(X[1]);  // ci 1
  loadx(X[2]);  // ci 2
  loadw(0, wA);
  for (int ci = 0; ci < 64; ci += 4) {
    // half 1: ci, ci+1
    loadw(ci + 1, wB);
    loadx(X[3]);                              // ci+3 (ci<=60 -> always valid)
    compute(wA, X[0]);                        // ci
    loadw(ci + 2, wA);
    if (ci + 4 < 64) loadx(X[0]);             // ci+4
    compute(wB, X[1]);                        // ci+1
    // half 2: ci+2, ci+3
    loadw(ci + 3, wB);
    if (ci + 5 < 64) loadx(X[1]);             // ci+5
    compute(wA, X[2]);                        // ci+2
    loadw((ci + 4 < 64) ? (ci + 4) : 0, wA);
    if (ci + 6 < 64) loadx(X[2]);             // ci+6
    compute(wB, X[3]);                        // ci+3
  }

  const float SIG1 = 0.73105857863000489f;   // sigmoid(1) fp32
  const float TANH1 = 0.76159415595576486f;  // tanh(1) fp32
  bool lb = (l < DIL), rb = (l >= LL - DIL);
#pragma unroll
  for (int j = 0; j < 4; ++j) {
    int cog = g * 4 + j;
    int cof = 64 + g * 4 + j;
    const float* pg = pc + ((layer * 4 + b) * 128 + cog) * 3;
    const float* pf = pc + ((layer * 4 + b) * 128 + cof) * 3;
    float S0g = pg[0], S1g = pg[1], S2g = pg[2];
    float S0f = pf[0], S1f = pf[1], S2f = pf[2];
    float bg = conv_b[layer * 128 + cog] + S0g + S1g + S2g;
    float bf = conv_b[layer * 128 + cof] + S0f + S1f + S2f;
    bg -= (lb ? S0g : 0.0f) + (rb ? S2g : 0.0f);
    bf -= (lb ? S0f : 0.0f) + (rb ? S2f : 0.0f);
    float vg = 0.0f, vf = 0.0f;
    float4 o;
    float* op = (float*)&o;
#pragma unroll
    for (int t = 0; t < 4; ++t) {
      float av = acc[j][t];
      float fv = acc[j + 4][t];
      float sg = lif_step(vg, av + bg);
      float sf = lif_step(vf, fv + bf);
      float gv = (sg != 0.0f) ? SIG1 : 0.5f;
      float tv = (sf != 0.0f) ? TANH1 : 0.0f;
      op[t] = gv * tv;
    }
    *(float4*)&y[(size_t)((b * 64 + cog) * LL + l) * 4] = o;
  }
}

// ---------------- 1x1 skip + res convs, MERGED ----------------
// grid (128, 4): l-tile 32, b. block 256. One block computes BOTH skip and
// res (y read once — proven R9/R10). NEW: y prefetch distance 1 -> 3 cp via
// ring-4 buffers (y loads are 64KB-strided -> L2/L3 hits; compute per cp is
// only ~64-128cy so 1-deep covered nothing). w stays 1-deep (contiguous,
// L1-hot). cp ascending = same summation order per output -> bit-exact.
__global__ __launch_bounds__(256) void skip_res_kernel(
    const float* __restrict__ y, const float* __restrict__ skipT,
    const float* __restrict__ resT, const float* __restrict__ skip_b,
    const float* __restrict__ res_b, float* __restrict__ tskip,
    float* __restrict__ x, int layer) {
  int tid = threadIdx.x;
  int lg = tid & 15;   // 16 l-groups of 2
  int cg = tid >> 4;   // 16 c-groups of 4
  int b = blockIdx.y;
  int l0 = blockIdx.x * 32 + lg * 2;
  int c0 = cg * 4;

  const float* ws_ = skipT + layer * 4096 + c0;  // [cp][c]
  const float* wr_ = resT + layer * 4096 + c0;
  const float* yb = y + (size_t)(b * 64 * LL + l0) * 4;

  v2f as_[16], ar_[16];  // [c4][l2][t-pair2]
#pragma unroll
  for (int q = 0; q < 16; ++q) {
    as_[q] = (v2f)(0.0f);
    ar_[q] = (v2f)(0.0f);
  }

  float4 Y0[4], Y1[4];  // ring: slot cp&3; Y0 = l0, Y1 = l0+1
  float4 wsa, wra, wsb, wrb;

  auto loady = [&](float4& d0, float4& d1, int cp) {
    d0 = *(const float4*)(yb + (size_t)cp * LL * 4);
    d1 = *(const float4*)(yb + (size_t)cp * LL * 4 + 4);
  };
  auto loadwv = [&](float4& s, float4& r, int cp) {
    s = *(const float4*)&ws_[cp * 64];
    r = *(const float4*)&wr_[cp * 64];
  };
  auto compq = [&](const float4& wsv4, const float4& wrv4,
                   const float4& yv0, const float4& yv1) {
    float wsv[4] = {wsv4.x, wsv4.y, wsv4.z, wsv4.w};
    float wrv[4] = {wrv4.x, wrv4.y, wrv4.z, wrv4.w};
    const v2f* yp0 = (const v2f*)&yv0;  // t01, t23
    const v2f* yp1 = (const v2f*)&yv1;
#pragma unroll
    for (int i = 0; i < 4; ++i) {
      v2f w2s, w2r;
      w2s.x = wsv[i]; w2s.y = wsv[i];
      w2r.x = wrv[i]; w2r.y = wrv[i];
      as_[i * 4 + 0] += w2s * yp0[0];
      as_[i * 4 + 1] += w2s * yp0[1];
      as_[i * 4 + 2] += w2s * yp1[0];
      as_[i * 4 + 3] += w2s * yp1[1];
      ar_[i * 4 + 0] += w2r * yp0[0];
      ar_[i * 4 + 1] += w2r * yp0[1];
      ar_[i * 4 + 2] += w2r * yp1[0];
      ar_[i * 4 + 3] += w2r * yp1[1];
    }
  };

  loady(Y0[0], Y1[0], 0);
  loady(Y0[1], Y1[1], 1);
  loady(Y0[2], Y1[2], 2);
  loadwv(wsa, wra, 0);
  for (int cp = 0; cp < 64; cp += 4) {
    loadwv(wsb, wrb, cp + 1);
    loady(Y0[3], Y1[3], cp + 3);                    // cp<=60 -> always valid
    compq(wsa, wra, Y0[0], Y1[0]);                  // cp
    loadwv(wsa, wra, cp + 2);
    if (cp + 4 < 64) loady(Y0[0], Y1[0], cp + 4);
    compq(wsb, wrb, Y0[1], Y1[1]);                  // cp+1
    loadwv(wsb, wrb, cp + 3);
    if (cp + 5 < 64) loady(Y0[1], Y1[1], cp + 5);
    compq(wsa, wra, Y0[2], Y1[2]);                  // cp+2
    loadwv(wsa, wra, (cp + 4 < 64) ? (cp + 4) : 0);
    if (cp + 6 < 64) loady(Y0[2], Y1[2], cp + 6);
    compq(wsb, wrb, Y0[3], Y1[3]);                  // cp+3
  }

#pragma unroll
  for (int i = 0; i < 4; ++i) {
    int c = c0 + i;
    float sb = skip_b[layer * 64 + c];
    float rb = res_b[layer * 64 + c];
    // skip -> tskip RMW (l0, l0+1)
    {
      size_t idx = (size_t)((b * 64 + c) * LL + l0) * 4;
      float4 o0, o1;
      if (layer == 0) {
        o0 = float4{0.f, 0.f, 0.f, 0.f};
        o1 = o0;
      } else {
        o0 = *(const float4*)&tskip[idx];
        o1 = *(const float4*)&tskip[idx + 4];
      }
      o0.x += as_[i * 4 + 0][0] + sb;
      o0.y += as_[i * 4 + 0][1] + sb;
      o0.z += as_[i * 4 + 1][0] + sb;
      o0.w += as_[i * 4 + 1][1] + sb;
      o1.x += as_[i * 4 + 2][0] + sb;
      o1.y += as_[i * 4 + 2][1] + sb;
      o1.z += as_[i * 4 + 3][0] + sb;
      o1.w += as_[i * 4 + 3][1] + sb;
      *(float4*)&tskip[idx] = o0;
      *(float4*)&tskip[idx + 4] = o1;
    }
    // res -> x RMW (l0, l0+1)
    {
      size_t idx = (size_t)((b * 64 + c) * XS + XPAD + l0) * 4;
      float4 o0 = *(const float4*)&x[idx];
      float4 o1 = *(const float4*)&x[idx + 4];
      o0.x += ar_[i * 4 + 0][0] + rb;
      o0.y += ar_[i * 4 + 0][1] + rb;
      o0.z += ar_[i * 4 + 1][0] + rb;
      o0.w += ar_[i * 4 + 1][1] + rb;
      o1.x += ar_[i * 4 + 2][0] + rb;
      o1.y += ar_[i * 4 + 2][1] + rb;
      o1.z += ar_[i * 4 + 3][0] + rb;
      o1.w += ar_[i * 4 + 3][1] + rb;
      *(float4*)&x[idx] = o0;
      *(float4*)&x[idx + 4] = o1;
    }
  }
}

// ---------------- output conv + LIF + sum over T ----------------
__global__ void out_kernel(const float* __restrict__ tskip,
                           const float* __restrict__ W_out,
                           const float* __restrict__ b_out,
                           float* __restrict__ out) {
  __shared__ float red[4][4][64];  // [grp][t][lq]
  int tid = threadIdx.x;
  int lq = tid & 63, grp = tid >> 6;
  int l = blockIdx.x * 64 + lq;
  int b = blockIdx.y;
  float acc[4] = {0.0f, 0.0f, 0.0f, 0.0f};
  for (int j = 0; j < 16; ++j) {
    int c = grp * 16 + j;
    float w = W_out[c];
    float4 sv = *(const float4*)&tskip[(size_t)((b * 64 + c) * LL + l) * 4];
    acc[0] += fmaxf(sv.x, 0.0f) * w;
    acc[1] += fmaxf(sv.y, 0.0f) * w;
    acc[2] += fmaxf(sv.z, 0.0f) * w;
    acc[3] += fmaxf(sv.w, 0.0f) * w;
  }
#pragma unroll
  for (int t = 0; t < 4; ++t) red[grp][t][lq] = acc[t];
  __syncthreads();
  if (grp == 0) {
    float bo = b_out[0];
    float v = 0.0f, s = 0.0f;
#pragma unroll
    for (int t = 0; t < 4; ++t) {
      float a = red[0][t][lq] + red[1][t][lq] + red[2][t][lq] + red[3][t][lq] + bo;
      s += lif_step(v, a);
    }
    out[b * LL + l] = s;
  }
}

extern "C" void kernel_launch(void* const* d_in, const int* in_sizes, int n_in,
                              void* d_out, int out_size, void* d_ws, size_t ws_size,
                              hipStream_t stream) {
  const float* audio   = (const float*)d_in[0];
  const int*   dstep   = (const int*)d_in[1];
  const float* W_in    = (const float*)d_in[2];
  const float* b_in    = (const float*)d_in[3];
  const float* demb_w1 = (const float*)d_in[4];
  const float* demb_b1 = (const float*)d_in[5];
  const float* demb_w2 = (const float*)d_in[6];
  const float* demb_b2 = (const float*)d_in[7];
  const float* dproj_w = (const float*)d_in[8];
  const float* dproj_b = (const float*)d_in[9];
  const float* conv_w  = (const float*)d_in[10];
  const float* conv_b  = (const float*)d_in[11];
  const float* skip_w  = (const float*)d_in[12];
  const float* skip_b  = (const float*)d_in[13];
  const float* res_w   = (const float*)d_in[14];
  const float* res_b   = (const float*)d_in[15];
  const float* W_out   = (const float*)d_in[16];
  const float* b_out   = (const float*)d_in[17];
  float* out = (float*)d_out;
  float* ws = (float*)d_ws;

  float* proj  = ws;                   // 2560 (unused after proj+pc merge)
  float* skipT = proj + 2560;          // 40960
  float* resT  = skipT + 40960;        // 40960
  float* pc    = resT + 40960;         // 15360
  float* wT    = pc + 15360;           // 10*16*64*24 = 245760
  float* x     = wT + 245760;          // 4*64*5120*4 = 5242880
  float* y     = x + 5242880;          // 4*64*4096*4 = 4194304
  float* tskip = y + 4194304;          // 4194304

  prep_kernel<<<10, 256, 0, stream>>>(skip_w, res_w, conv_w, skipT, resT, wT);
  proj_pc_kernel<<<10, 256, 0, stream>>>(dstep, demb_w1, demb_b1, demb_w2,
                                         demb_b2, dproj_w, dproj_b, conv_w, pc);
  encode_lif_kernel<<<dim3(64, 4), 256, 0, stream>>>(audio, W_in, b_in, x);

  for (int i = 0; i < NLAYERS; ++i) {
    dim3 gc(16, 16, 4);
    switch (i) {
      case 0: layer_conv_kernel<1><<<gc, 256, 0, stream>>>(x, wT, conv_b, pc, y, i); break;
      case 1: layer_conv_kernel<2><<<gc, 256, 0, stream>>>(x, wT, conv_b, pc, y, i); break;
      case 2: layer_conv_kernel<4><<<gc, 256, 0, stream>>>(x, wT, conv_b, pc, y, i); break;
      case 3: layer_conv_kernel<8><<<gc, 256, 0, stream>>>(x, wT, conv_b, pc, y, i); break;
      case 4: layer_conv_kernel<16><<<gc, 256, 0, stream>>>(x, wT, conv_b, pc, y, i); break;
      case 5: layer_conv_kernel<32><<<gc, 256, 0, stream>>>(x, wT, conv_b, pc, y, i); break;
      case 6: layer_conv_kernel<64><<<gc, 256, 0, stream>>>(x, wT, conv_b, pc, y, i); break;
      case 7: layer_conv_kernel<128><<<gc, 256, 0, stream>>>(x, wT, conv_b, pc, y, i); break;
      case 8: layer_conv_kernel<256><<<gc, 256, 0, stream>>>(x, wT, conv_b, pc, y, i); break;
      case 9: layer_conv_kernel<512><<<gc, 256, 0, stream>>>(x, wT, conv_b, pc, y, i); break;
    }
    skip_res_kernel<<<dim3(128, 4), 256, 0, stream>>>(y, skipT, resT, skip_b,
                                                      res_b, tskip, x, i);
  }
  out_kernel<<<dim3(64, 4), 256, 0, stream>>>(tskip, W_out, b_out, out);
}

// Round 12
// 769.600 us; speedup vs baseline: 1.1184x; 1.1184x over previous
//
#include <hip/hip_runtime.h>

#define LL 4096
#define NB 4
#define NC 64
#define NT 4
#define NLAYERS 10
#define XS 5120   // padded x row stride (in l units; x is [B][C][XS][4])
#define XPAD 512  // left/right zero pad (>= max dilation)

typedef float v2f __attribute__((ext_vector_type(2)));

// Constant-address-space cast: forces s_load for wave-uniform weight reads ->
// weights live in SGPRs, FMA is v_fmac_f32 acc, s_w, v_x (proven R6: 47.4us).
typedef __attribute__((address_space(4))) const float cfloat;
__device__ __forceinline__ cfloat* to_constant(const float* p) {
  return (cfloat*)(unsigned long long)p;
}

// ---------------- Threefry-2x32, key = (0, 42), 20 rounds ----------------
__device__ __forceinline__ void threefry2x32(unsigned x0, unsigned x1,
                                             unsigned& o0, unsigned& o1) {
  const unsigned ks0 = 0u, ks1 = 42u;
  const unsigned ks2 = 0x1BD11BDAu ^ ks0 ^ ks1;
  const unsigned ks[3] = {ks0, ks1, ks2};
  const unsigned r0[4] = {13u, 15u, 26u, 6u};
  const unsigned r1[4] = {17u, 29u, 16u, 24u};
  x0 += ks0; x1 += ks1;
#pragma unroll
  for (int g = 0; g < 5; ++g) {
    const unsigned* rr = (g & 1) ? r1 : r0;
#pragma unroll
    for (int j = 0; j < 4; ++j) {
      x0 += x1;
      unsigned r = rr[j];
      x1 = (x1 << r) | (x1 >> (32u - r));
      x1 ^= x0;
    }
    x0 += ks[(g + 1) % 3];
    x1 += ks[(g + 2) % 3] + (unsigned)(g + 1);
  }
  o0 = x0; o1 = x1;
}

__device__ __forceinline__ float u01(unsigned bits) {
  return __uint_as_float((bits >> 9) | 0x3f800000u) - 1.0f;
}

// LIF step: v = v + (x - v)/1.2 ; spike = v>=0.5 ; v *= (1-spike)
__device__ __forceinline__ float lif_step(float& v, float xt) {
  v = v + (xt - v) / 1.2f;
  float s = (v >= 0.5f) ? 1.0f : 0.0f;
  v = v * (1.0f - s);
  return s;
}

// ---------------- prep: transpose skip/res 1x1 + build wT ----------------
// skipT/resT: [i][c'][c]. wT: [i][g16][ci][k][col8], col<4 gate co=g*4+col,
// col>=4 filt co=64+g*4+col-4. (R6 layout.) Widened 10 -> (10,8) blocks:
// slice y handles 1/8 of each loop (was 10 blocks = 10 CUs for 1.3MB of
// strided shuffling; R11 showed narrow prep-side kernels cost real time).
__global__ void prep_kernel(const float* __restrict__ skip_w,
                            const float* __restrict__ res_w,
                            const float* __restrict__ conv_w,
                            float* __restrict__ skipT,
                            float* __restrict__ resT,
                            float* __restrict__ wT) {
  int i = blockIdx.x;
  int slice = blockIdx.y;  // 0..7
  for (int idx = slice * 512 + threadIdx.x; idx < (slice + 1) * 512; idx += 256) {
    int c = idx >> 6, cp = idx & 63;
    skipT[i * 4096 + cp * 64 + c] = skip_w[i * 4096 + c * 64 + cp];
    resT[i * 4096 + cp * 64 + c] = res_w[i * 4096 + c * 64 + cp];
  }
  for (int idx = slice * 3072 + threadIdx.x; idx < (slice + 1) * 3072; idx += 256) {
    int col = idx & 7;
    int r = idx >> 3;
    int k = r % 3; r /= 3;
    int ci = r % 64;
    int g = r / 64;  // 0..15
    int co = (col < 4) ? (g * 4 + col) : (64 + g * 4 + (col - 4));
    wT[i * 24576 + idx] = conv_w[(i * 128 + co) * 192 + ci * 3 + k];
  }
}

// ---------------- diffusion-step embedding -> proj[i][b][c] ----------------
// (R10 version restored — the R11 proj+pc merge at 10 blocks was 133us.)
__global__ void proj_kernel(const int* __restrict__ dstep,
                            const float* __restrict__ w1, const float* __restrict__ b1,
                            const float* __restrict__ w2, const float* __restrict__ b2,
                            const float* __restrict__ pw, const float* __restrict__ pb,
                            float* __restrict__ proj) {
  __shared__ float e1[NB][NC];
  __shared__ float e2[NB][NC];
  int i = blockIdx.x;
  int tid = threadIdx.x;
  int b = tid >> 6, c = tid & 63;
  float d = (float)dstep[b];
  float v = d * w1[i * 64 + c] + b1[i * 64 + c];
  v = v / (1.0f + expf(-v));  // silu
  e1[b][c] = v;
  __syncthreads();
  float a = b2[i * 64 + c];
  for (int cp = 0; cp < 64; ++cp) a += e1[b][cp] * w2[(i * 64 + c) * 64 + cp];
  e2[b][c] = a;
  __syncthreads();
  float p = pb[i * 64 + c];
  for (int cp = 0; cp < 64; ++cp) p += e2[b][cp] * pw[(i * 64 + c) * 64 + cp];
  proj[(i * 4 + b) * 64 + c] = p;
}

// ---------------- per-(layer,b,co) proj-weighted tap sums S0,S1,S2 ----------------
__global__ void pc_kernel(const float* __restrict__ proj,
                          const float* __restrict__ conv_w,
                          float* __restrict__ pc) {
  __shared__ float pv[64];
  int layer = blockIdx.x, b = blockIdx.y;
  int tid = threadIdx.x;  // 128
  if (tid < 64) pv[tid] = proj[(layer * 4 + b) * 64 + tid];
  __syncthreads();
  int co = tid;
  const float* w = conv_w + (layer * 128 + co) * 192;
  float s0 = 0.0f, s1 = 0.0f, s2 = 0.0f;
  for (int ci = 0; ci < 64; ++ci) {
    float p = pv[ci];
    s0 += p * w[ci * 3 + 0];
    s1 += p * w[ci * 3 + 1];
    s2 += p * w[ci * 3 + 2];
  }
  float* o = pc + ((layer * 4 + b) * 128 + co) * 3;
  o[0] = s0; o[1] = s1; o[2] = s2;
}

// ---------------- Poisson encode + input conv + LIF -> x [B][C][XS][4] ---------
// Pad-zeroing folded in (padzero dispatch removed, kept from R11 — the one
// R11 piece with no evidence against it): block (lx, b) zeros the pad
// margins of row (b, c=lx); 64 lx-blocks x 4 b cover all 256 rows. Pads and
// interior are disjoint addresses; x pads stay zero across layers since
// skip_res only writes the interior.
__global__ void encode_lif_kernel(const float* __restrict__ audio,
                                  const float* __restrict__ W_in,
                                  const float* __restrict__ b_in,
                                  float* __restrict__ x) {
  int tid = threadIdx.x;
  int lq = tid & 63, grp = tid >> 6;
  int l = blockIdx.x * 64 + lq;
  int b = blockIdx.y;
  // zero pads for row (b, c = blockIdx.x)
  {
    float* base = x + (size_t)((b * 64 + blockIdx.x) * XS) * 4;
    for (int q = tid; q < XPAD; q += 256) {
      *(float4*)&base[q * 4] = float4{0.f, 0.f, 0.f, 0.f};
      *(float4*)&base[(XPAD + LL + q) * 4] = float4{0.f, 0.f, 0.f, 0.f};
    }
  }
  float a = audio[b * LL + l];
  unsigned p0 = (unsigned)(b * LL + l);  // t=0 (o0), t=2 (o1)
  unsigned p1 = 16384u + p0;             // t=1 (o0), t=3 (o1)
  unsigned o00, o01, o10, o11;
  threefry2x32(p0, p0 + 32768u, o00, o01);
  threefry2x32(p1, p1 + 32768u, o10, o11);
  float sp[4];
  sp[0] = (u01(o00) < a) ? 1.0f : 0.0f;
  sp[1] = (u01(o10) < a) ? 1.0f : 0.0f;
  sp[2] = (u01(o01) < a) ? 1.0f : 0.0f;
  sp[3] = (u01(o11) < a) ? 1.0f : 0.0f;
  for (int j = 0; j < 16; ++j) {
    int c = grp * 16 + j;
    float w = W_in[c], bb = b_in[c];
    float v = 0.0f;
    float4 o;
    float* op = (float*)&o;
#pragma unroll
    for (int t = 0; t < 4; ++t) op[t] = lif_step(v, w * sp[t] + bb);
    *(float4*)&x[(size_t)((b * 64 + c) * XS + XPAD + l) * 4] = o;
  }
}

// ---------------- dilated conv + LIF + gate -> y [B][64][LL][4] ----------------
// EXACT R6 kernel (proven 47.4-48.3us across R6/R10; ring-4 distance-3
// prefetch regressed TWICE (R7, R11) -> 1-deep at 40 VGPR is the optimum).
// grid (16, 16, 4), block 256: l-tile 256, co-group g (16 x (4 gate +
// 4 filt)), b. Thread: 1 l, 4 t, 8 co; acc[8][4] scalar f32. Weights
// wave-uniform -> s_load/SGPR (constant addr space), wA/wB double-buffer
// 1 ci ahead; x float4 double-buffer 1 ci ahead.
// Accumulation order (ci asc, k asc) -> bit-exact.
template <int DIL>
__global__ __launch_bounds__(256) void layer_conv_kernel(
    const float* __restrict__ x, const float* __restrict__ wT,
    const float* __restrict__ conv_b, const float* __restrict__ pc,
    float* __restrict__ y, int layer) {
  int tid = threadIdx.x;
  int g = blockIdx.y;   // 0..15
  int b = blockIdx.z;
  int l = blockIdx.x * 256 + tid;
  cfloat* cw = to_constant(wT + (size_t)(layer * 16 + g) * 1536);

  const float* px = x + (size_t)(b * 64 * XS + XPAD + l) * 4;  // ci=0 row

  float acc[8][4];  // [col][t]; col 0-3 gate, 4-7 filt
#pragma unroll
  for (int j = 0; j < 8; ++j)
#pragma unroll
    for (int t = 0; t < 4; ++t) acc[j][t] = 0.0f;

  float4 xa[3], xb[3];      // [k] = 4 t values
  float wA[3][8], wB[3][8]; // [k][col] wave-uniform -> SGPRs

  auto loadx = [&](float4* dst) {
    dst[0] = *(const float4*)(px - (size_t)DIL * 4);
    dst[1] = *(const float4*)px;
    dst[2] = *(const float4*)(px + (size_t)DIL * 4);
    px += (size_t)XS * 4;
  };
  auto loadw = [&](int ci, float (*w)[8]) {
#pragma unroll
    for (int k = 0; k < 3; ++k)
#pragma unroll
      for (int j = 0; j < 8; ++j)
        w[k][j] = cw[(ci * 3 + k) * 8 + j];  // s_load (merged)
  };
  auto compute = [&](const float (*w)[8], const float4* xv) {
#pragma unroll
    for (int k = 0; k < 3; ++k) {
      const float* xk = (const float*)&xv[k];
#pragma unroll
      for (int t = 0; t < 4; ++t) {
        float xq = xk[t];
#pragma unroll
        for (int j = 0; j < 8; ++j)
          acc[j][t] += w[k][j] * xq;  // v_fmac_f32 acc, s, v
      }
    }
  };

  loadx(xa);
  loadw(0, wA);
  for (int ci = 0; ci < 64; ci += 2) {
    loadx(xb);
    loadw(ci + 1, wB);
    compute(wA, xa);
    if (ci + 2 < 64) {
      loadx(xa);
      loadw(ci + 2, wA);
    }
    compute(wB, xb);
  }

  const float SIG1 = 0.73105857863000489f;   // sigmoid(1) fp32
  const float TANH1 = 0.76159415595576486f;  // tanh(1) fp32
  bool lb = (l < DIL), rb = (l >= LL - DIL);
#pragma unroll
  for (int j = 0; j < 4; ++j) {
    int cog = g * 4 + j;
    int cof = 64 + g * 4 + j;
    const float* pg = pc + ((layer * 4 + b) * 128 + cog) * 3;
    const float* pf = pc + ((layer * 4 + b) * 128 + cof) * 3;
    float S0g = pg[0], S1g = pg[1], S2g = pg[2];
    float S0f = pf[0], S1f = pf[1], S2f = pf[2];
    float bg = conv_b[layer * 128 + cog] + S0g + S1g + S2g;
    float bf = conv_b[layer * 128 + cof] + S0f + S1f + S2f;
    bg -= (lb ? S0g : 0.0f) + (rb ? S2g : 0.0f);
    bf -= (lb ? S0f : 0.0f) + (rb ? S2f : 0.0f);
    float vg = 0.0f, vf = 0.0f;
    float4 o;
    float* op = (float*)&o;
#pragma unroll
    for (int t = 0; t < 4; ++t) {
      float av = acc[j][t];
      float fv = acc[j + 4][t];
      float sg = lif_step(vg, av + bg);
      float sf = lif_step(vf, fv + bf);
      float gv = (sg != 0.0f) ? SIG1 : 0.5f;
      float tv = (sf != 0.0f) ? TANH1 : 0.0f;
      op[t] = gv * tv;
    }
    *(float4*)&y[(size_t)((b * 64 + cog) * LL + l) * 4] = o;
  }
}

// ---------------- 1x1 skip + res convs, MERGED (proven R9/R10) ----------------
// grid (128, 4): l-tile 32, b. block 256. One block computes BOTH skip and
// res for its tile -> y tile read ONCE. Thread: 4 c x 2 l x 4 t x
// {skip,res} (32 v2f acc). Per cp: skip-w float4 + res-w float4 + 2 y
// float4, prefetched 1 cp ahead (R11's ring-4 on y showed no gain —
// reverted to the proven R10 form). cp ascending -> bit-exact.
__global__ __launch_bounds__(256) void skip_res_kernel(
    const float* __restrict__ y, const float* __restrict__ skipT,
    const float* __restrict__ resT, const float* __restrict__ skip_b,
    const float* __restrict__ res_b, float* __restrict__ tskip,
    float* __restrict__ x, int layer) {
  int tid = threadIdx.x;
  int lg = tid & 15;   // 16 l-groups of 2
  int cg = tid >> 4;   // 16 c-groups of 4
  int b = blockIdx.y;
  int l0 = blockIdx.x * 32 + lg * 2;
  int c0 = cg * 4;

  const float* ws_ = skipT + layer * 4096 + c0;  // [cp][c]
  const float* wr_ = resT + layer * 4096 + c0;
  const float* yb = y + (size_t)(b * 64 * LL + l0) * 4;

  v2f as_[16], ar_[16];  // [c4][l2][t-pair2]
#pragma unroll
  for (int q = 0; q < 16; ++q) {
    as_[q] = (v2f)(0.0f);
    ar_[q] = (v2f)(0.0f);
  }

  float4 wsa = *(const float4*)&ws_[0];
  float4 wra = *(const float4*)&wr_[0];
  float4 y0a = *(const float4*)yb;             // l0, t0..3
  float4 y1a = *(const float4*)(yb + 4);       // l0+1, t0..3

  for (int cp = 0; cp < 64; ++cp) {
    int cpn = (cp < 63) ? cp + 1 : 63;
    float4 wsb = *(const float4*)&ws_[cpn * 64];
    float4 wrb = *(const float4*)&wr_[cpn * 64];
    float4 y0b = *(const float4*)(yb + (size_t)cpn * LL * 4);
    float4 y1b = *(const float4*)(yb + (size_t)cpn * LL * 4 + 4);

    float wsv[4] = {wsa.x, wsa.y, wsa.z, wsa.w};
    float wrv[4] = {wra.x, wra.y, wra.z, wra.w};
    const v2f* yp0 = (const v2f*)&y0a;  // t01, t23
    const v2f* yp1 = (const v2f*)&y1a;
#pragma unroll
    for (int i = 0; i < 4; ++i) {
      v2f w2s, w2r;
      w2s.x = wsv[i]; w2s.y = wsv[i];
      w2r.x = wrv[i]; w2r.y = wrv[i];
      as_[i * 4 + 0] += w2s * yp0[0];
      as_[i * 4 + 1] += w2s * yp0[1];
      as_[i * 4 + 2] += w2s * yp1[0];
      as_[i * 4 + 3] += w2s * yp1[1];
      ar_[i * 4 + 0] += w2r * yp0[0];
      ar_[i * 4 + 1] += w2r * yp0[1];
      ar_[i * 4 + 2] += w2r * yp1[0];
      ar_[i * 4 + 3] += w2r * yp1[1];
    }
    wsa = wsb; wra = wrb; y0a = y0b; y1a = y1b;
  }

#pragma unroll
  for (int i = 0; i < 4; ++i) {
    int c = c0 + i;
    float sb = skip_b[layer * 64 + c];
    float rb = res_b[layer * 64 + c];
    // skip -> tskip RMW (l0, l0+1)
    {
      size_t idx = (size_t)((b * 64 + c) * LL + l0) * 4;
      float4 o0, o1;
      if (layer == 0) {
        o0 = float4{0.f, 0.f, 0.f, 0.f};
        o1 = o0;
      } else {
        o0 = *(const float4*)&tskip[idx];
        o1 = *(const float4*)&tskip[idx + 4];
      }
      o0.x += as_[i * 4 + 0][0] + sb;
      o0.y += as_[i * 4 + 0][1] + sb;
      o0.z += as_[i * 4 + 1][0] + sb;
      o0.w += as_[i * 4 + 1][1] + sb;
      o1.x += as_[i * 4 + 2][0] + sb;
      o1.y += as_[i * 4 + 2][1] + sb;
      o1.z += as_[i * 4 + 3][0] + sb;
      o1.w += as_[i * 4 + 3][1] + sb;
      *(float4*)&tskip[idx] = o0;
      *(float4*)&tskip[idx + 4] = o1;
    }
    // res -> x RMW (l0, l0+1)
    {
      size_t idx = (size_t)((b * 64 + c) * XS + XPAD + l0) * 4;
      float4 o0 = *(const float4*)&x[idx];
      float4 o1 = *(const float4*)&x[idx + 4];
      o0.x += ar_[i * 4 + 0][0] + rb;
      o0.y += ar_[i * 4 + 0][1] + rb;
      o0.z += ar_[i * 4 + 1][0] + rb;
      o0.w += ar_[i * 4 + 1][1] + rb;
      o1.x += ar_[i * 4 + 2][0] + rb;
      o1.y += ar_[i * 4 + 2][1] + rb;
      o1.z += ar_[i * 4 + 3][0] + rb;
      o1.w += ar_[i * 4 + 3][1] + rb;
      *(float4*)&x[idx] = o0;
      *(float4*)&x[idx + 4] = o1;
    }
  }
}

// ---------------- output conv + LIF + sum over T ----------------
__global__ void out_kernel(const float* __restrict__ tskip,
                           const float* __restrict__ W_out,
                           const float* __restrict__ b_out,
                           float* __restrict__ out) {
  __shared__ float red[4][4][64];  // [grp][t][lq]
  int tid = threadIdx.x;
  int lq = tid & 63, grp = tid >> 6;
  int l = blockIdx.x * 64 + lq;
  int b = blockIdx.y;
  float acc[4] = {0.0f, 0.0f, 0.0f, 0.0f};
  for (int j = 0; j < 16; ++j) {
    int c = grp * 16 + j;
    float w = W_out[c];
    float4 sv = *(const float4*)&tskip[(size_t)((b * 64 + c) * LL + l) * 4];
    acc[0] += fmaxf(sv.x, 0.0f) * w;
    acc[1] += fmaxf(sv.y, 0.0f) * w;
    acc[2] += fmaxf(sv.z, 0.0f) * w;
    acc[3] += fmaxf(sv.w, 0.0f) * w;
  }
#pragma unroll
  for (int t = 0; t < 4; ++t) red[grp][t][lq] = acc[t];
  __syncthreads();
  if (grp == 0) {
    float bo = b_out[0];
    float v = 0.0f, s = 0.0f;
#pragma unroll
    for (int t = 0; t < 4; ++t) {
      float a = red[0][t][lq] + red[1][t][lq] + red[2][t][lq] + red[3][t][lq] + bo;
      s += lif_step(v, a);
    }
    out[b * LL + l] = s;
  }
}

extern "C" void kernel_launch(void* const* d_in, const int* in_sizes, int n_in,
                              void* d_out, int out_size, void* d_ws, size_t ws_size,
                              hipStream_t stream) {
  const float* audio   = (const float*)d_in[0];
  const int*   dstep   = (const int*)d_in[1];
  const float* W_in    = (const float*)d_in[2];
  const float* b_in    = (const float*)d_in[3];
  const float* demb_w1 = (const float*)d_in[4];
  const float* demb_b1 = (const float*)d_in[5];
  const float* demb_w2 = (const float*)d_in[6];
  const float* demb_b2 = (const float*)d_in[7];
  const float* dproj_w = (const float*)d_in[8];
  const float* dproj_b = (const float*)d_in[9];
  const float* conv_w  = (const float*)d_in[10];
  const float* conv_b  = (const float*)d_in[11];
  const float* skip_w  = (const float*)d_in[12];
  const float* skip_b  = (const float*)d_in[13];
  const float* res_w   = (const float*)d_in[14];
  const float* res_b   = (const float*)d_in[15];
  const float* W_out   = (const float*)d_in[16];
  const float* b_out   = (const float*)d_in[17];
  float* out = (float*)d_out;
  float* ws = (float*)d_ws;

  float* proj  = ws;                   // 2560
  float* skipT = proj + 2560;          // 40960
  float* resT  = skipT + 40960;        // 40960
  float* pc    = resT + 40960;         // 15360
  float* wT    = pc + 15360;           // 10*16*64*24 = 245760
  float* x     = wT + 245760;          // 4*64*5120*4 = 5242880
  float* y     = x + 5242880;          // 4*64*4096*4 = 4194304
  float* tskip = y + 4194304;          // 4194304

  prep_kernel<<<dim3(10, 8), 256, 0, stream>>>(skip_w, res_w, conv_w, skipT,
                                               resT, wT);
  proj_kernel<<<10, 256, 0, stream>>>(dstep, demb_w1, demb_b1, demb_w2, demb_b2,
                                      dproj_w, dproj_b, proj);
  pc_kernel<<<dim3(10, 4), 128, 0, stream>>>(proj, conv_w, pc);
  encode_lif_kernel<<<dim3(64, 4), 256, 0, stream>>>(audio, W_in, b_in, x);

  for (int i = 0; i < NLAYERS; ++i) {
    dim3 gc(16, 16, 4);
    switch (i) {
      case 0: layer_conv_kernel<1><<<gc, 256, 0, stream>>>(x, wT, conv_b, pc, y, i); break;
      case 1: layer_conv_kernel<2><<<gc, 256, 0, stream>>>(x, wT, conv_b, pc, y, i); break;
      case 2: layer_conv_kernel<4><<<gc, 256, 0, stream>>>(x, wT, conv_b, pc, y, i); break;
      case 3: layer_conv_kernel<8><<<gc, 256, 0, stream>>>(x, wT, conv_b, pc, y, i); break;
      case 4: layer_conv_kernel<16><<<gc, 256, 0, stream>>>(x, wT, conv_b, pc, y, i); break;
      case 5: layer_conv_kernel<32><<<gc, 256, 0, stream>>>(x, wT, conv_b, pc, y, i); break;
      case 6: layer_conv_kernel<64><<<gc, 256, 0, stream>>>(x, wT, conv_b, pc, y, i); break;
      case 7: layer_conv_kernel<128><<<gc, 256, 0, stream>>>(x, wT, conv_b, pc, y, i); break;
      case 8: layer_conv_kernel<256><<<gc, 256, 0, stream>>>(x, wT, conv_b, pc, y, i); break;
      case 9: layer_conv_kernel<512><<<gc, 256, 0, stream>>>(x, wT, conv_b, pc, y, i); break;
    }
    skip_res_kernel<<<dim3(128, 4), 256, 0, stream>>>(y, skipT, resT, skip_b,
                                                      res_b, tskip, x, i);
  }
  out_kernel<<<dim3(64, 4), 256, 0, stream>>>(tskip, W_out, b_out, out);
}

// Round 13
// 764.726 us; speedup vs baseline: 1.1256x; 1.0064x over previous
//
#include <hip/hip_runtime.h>

#define LL 4096
#define NB 4
#define NC 64
#define NT 4
#define NLAYERS 10
#define XS 5120   // padded x row stride (in l units; x is [B][C][XS][4])
#define XPAD 512  // left/right zero pad (>= max dilation)

typedef float v2f __attribute__((ext_vector_type(2)));

// Constant-address-space cast: forces s_load for wave-uniform weight reads ->
// weights live in SGPRs, FMA is v_fmac_f32 acc, s_w, v_x (proven R6: 47.4us).
typedef __attribute__((address_space(4))) const float cfloat;
__device__ __forceinline__ cfloat* to_constant(const float* p) {
  return (cfloat*)(unsigned long long)p;
}

// ---------------- Threefry-2x32, key = (0, 42), 20 rounds ----------------
__device__ __forceinline__ void threefry2x32(unsigned x0, unsigned x1,
                                             unsigned& o0, unsigned& o1) {
  const unsigned ks0 = 0u, ks1 = 42u;
  const unsigned ks2 = 0x1BD11BDAu ^ ks0 ^ ks1;
  const unsigned ks[3] = {ks0, ks1, ks2};
  const unsigned r0[4] = {13u, 15u, 26u, 6u};
  const unsigned r1[4] = {17u, 29u, 16u, 24u};
  x0 += ks0; x1 += ks1;
#pragma unroll
  for (int g = 0; g < 5; ++g) {
    const unsigned* rr = (g & 1) ? r1 : r0;
#pragma unroll
    for (int j = 0; j < 4; ++j) {
      x0 += x1;
      unsigned r = rr[j];
      x1 = (x1 << r) | (x1 >> (32u - r));
      x1 ^= x0;
    }
    x0 += ks[(g + 1) % 3];
    x1 += ks[(g + 2) % 3] + (unsigned)(g + 1);
  }
  o0 = x0; o1 = x1;
}

__device__ __forceinline__ float u01(unsigned bits) {
  return __uint_as_float((bits >> 9) | 0x3f800000u) - 1.0f;
}

// LIF step: v = v + (x - v)/1.2 ; spike = v>=0.5 ; v *= (1-spike)
__device__ __forceinline__ float lif_step(float& v, float xt) {
  v = v + (xt - v) / 1.2f;
  float s = (v >= 0.5f) ? 1.0f : 0.0f;
  v = v * (1.0f - s);
  return s;
}

// ---------------- prep: transpose skip/res 1x1 + build wT ----------------
// skipT/resT: [i][c'][c]. wT: [i][g16][ci][k][col8], col<4 gate co=g*4+col,
// col>=4 filt co=64+g*4+col-4. (R6 layout.) (10,8) blocks — proven R12.
__global__ void prep_kernel(const float* __restrict__ skip_w,
                            const float* __restrict__ res_w,
                            const float* __restrict__ conv_w,
                            float* __restrict__ skipT,
                            float* __restrict__ resT,
                            float* __restrict__ wT) {
  int i = blockIdx.x;
  int slice = blockIdx.y;  // 0..7
  for (int idx = slice * 512 + threadIdx.x; idx < (slice + 1) * 512; idx += 256) {
    int c = idx >> 6, cp = idx & 63;
    skipT[i * 4096 + cp * 64 + c] = skip_w[i * 4096 + c * 64 + cp];
    resT[i * 4096 + cp * 64 + c] = res_w[i * 4096 + c * 64 + cp];
  }
  for (int idx = slice * 3072 + threadIdx.x; idx < (slice + 1) * 3072; idx += 256) {
    int col = idx & 7;
    int r = idx >> 3;
    int k = r % 3; r /= 3;
    int ci = r % 64;
    int g = r / 64;  // 0..15
    int co = (col < 4) ? (g * 4 + col) : (64 + g * 4 + (col - 4));
    wT[i * 24576 + idx] = conv_w[(i * 128 + co) * 192 + ci * 3 + k];
  }
}

// ---------------- diffusion-step embedding -> proj[i][b][c] ----------------
__global__ void proj_kernel(const int* __restrict__ dstep,
                            const float* __restrict__ w1, const float* __restrict__ b1,
                            const float* __restrict__ w2, const float* __restrict__ b2,
                            const float* __restrict__ pw, const float* __restrict__ pb,
                            float* __restrict__ proj) {
  __shared__ float e1[NB][NC];
  __shared__ float e2[NB][NC];
  int i = blockIdx.x;
  int tid = threadIdx.x;
  int b = tid >> 6, c = tid & 63;
  float d = (float)dstep[b];
  float v = d * w1[i * 64 + c] + b1[i * 64 + c];
  v = v / (1.0f + expf(-v));  // silu
  e1[b][c] = v;
  __syncthreads();
  float a = b2[i * 64 + c];
  for (int cp = 0; cp < 64; ++cp) a += e1[b][cp] * w2[(i * 64 + c) * 64 + cp];
  e2[b][c] = a;
  __syncthreads();
  float p = pb[i * 64 + c];
  for (int cp = 0; cp < 64; ++cp) p += e2[b][cp] * pw[(i * 64 + c) * 64 + cp];
  proj[(i * 4 + b) * 64 + c] = p;
}

// ---------------- per-(layer,b,co) proj-weighted tap sums S0,S1,S2 ----------------
__global__ void pc_kernel(const float* __restrict__ proj,
                          const float* __restrict__ conv_w,
                          float* __restrict__ pc) {
  __shared__ float pv[64];
  int layer = blockIdx.x, b = blockIdx.y;
  int tid = threadIdx.x;  // 128
  if (tid < 64) pv[tid] = proj[(layer * 4 + b) * 64 + tid];
  __syncthreads();
  int co = tid;
  const float* w = conv_w + (layer * 128 + co) * 192;
  float s0 = 0.0f, s1 = 0.0f, s2 = 0.0f;
  for (int ci = 0; ci < 64; ++ci) {
    float p = pv[ci];
    s0 += p * w[ci * 3 + 0];
    s1 += p * w[ci * 3 + 1];
    s2 += p * w[ci * 3 + 2];
  }
  float* o = pc + ((layer * 4 + b) * 128 + co) * 3;
  o[0] = s0; o[1] = s1; o[2] = s2;
}

// ---------------- Poisson encode + input conv + LIF -> x [B][C][XS][4] ---------
// Pad-zeroing folded in (proven R12): block (lx, b) zeros the pad margins of
// row (b, c=lx). Pads and interior are disjoint; pads stay zero across layers.
__global__ void encode_lif_kernel(const float* __restrict__ audio,
                                  const float* __restrict__ W_in,
                                  const float* __restrict__ b_in,
                                  float* __restrict__ x) {
  int tid = threadIdx.x;
  int lq = tid & 63, grp = tid >> 6;
  int l = blockIdx.x * 64 + lq;
  int b = blockIdx.y;
  // zero pads for row (b, c = blockIdx.x)
  {
    float* base = x + (size_t)((b * 64 + blockIdx.x) * XS) * 4;
    for (int q = tid; q < XPAD; q += 256) {
      *(float4*)&base[q * 4] = float4{0.f, 0.f, 0.f, 0.f};
      *(float4*)&base[(XPAD + LL + q) * 4] = float4{0.f, 0.f, 0.f, 0.f};
    }
  }
  float a = audio[b * LL + l];
  unsigned p0 = (unsigned)(b * LL + l);  // t=0 (o0), t=2 (o1)
  unsigned p1 = 16384u + p0;             // t=1 (o0), t=3 (o1)
  unsigned o00, o01, o10, o11;
  threefry2x32(p0, p0 + 32768u, o00, o01);
  threefry2x32(p1, p1 + 32768u, o10, o11);
  float sp[4];
  sp[0] = (u01(o00) < a) ? 1.0f : 0.0f;
  sp[1] = (u01(o10) < a) ? 1.0f : 0.0f;
  sp[2] = (u01(o01) < a) ? 1.0f : 0.0f;
  sp[3] = (u01(o11) < a) ? 1.0f : 0.0f;
  for (int j = 0; j < 16; ++j) {
    int c = grp * 16 + j;
    float w = W_in[c], bb = b_in[c];
    float v = 0.0f;
    float4 o;
    float* op = (float*)&o;
#pragma unroll
    for (int t = 0; t < 4; ++t) op[t] = lif_step(v, w * sp[t] + bb);
    *(float4*)&x[(size_t)((b * 64 + c) * XS + XPAD + l) * 4] = o;
  }
}

// ---------------- dilated conv + LIF + gate -> y [B][64][LL][4] ----------------
// R6 structure (SGPR weights via constant addr space, wA/wB 1-ci double
// buffer, x float4 1-ci double buffer — proven 47.4-48.1us) with ONE change:
// the MAC is t-PAIRED — acc2[j][pair] += w * xpair. w is SGPR-resident and
// wave-uniform, so VOP3P v_pk_fma_f32 takes it as the one allowed SGPR
// operand with op_sel broadcast: NOTHING to pack (unlike R0-R5's VGPR
// splats). FMA issue halves: 6144 v_fmac -> 3072 v_pk_fma (20.5 -> 10.2us
// of pure issue at 4 waves/SIMD). Per-element add order over (ci,k)
// unchanged -> bit-exact.
template <int DIL>
__global__ __launch_bounds__(256) void layer_conv_kernel(
    const float* __restrict__ x, const float* __restrict__ wT,
    const float* __restrict__ conv_b, const float* __restrict__ pc,
    float* __restrict__ y, int layer) {
  int tid = threadIdx.x;
  int g = blockIdx.y;   // 0..15
  int b = blockIdx.z;
  int l = blockIdx.x * 256 + tid;
  cfloat* cw = to_constant(wT + (size_t)(layer * 16 + g) * 1536);

  const float* px = x + (size_t)(b * 64 * XS + XPAD + l) * 4;  // ci=0 row

  v2f acc2[8][2];  // [col][t-pair]; col 0-3 gate, 4-7 filt
#pragma unroll
  for (int j = 0; j < 8; ++j) {
    acc2[j][0] = (v2f)(0.0f);
    acc2[j][1] = (v2f)(0.0f);
  }

  float4 xa[3], xb[3];      // [k] = 4 t values
  float wA[3][8], wB[3][8]; // [k][col] wave-uniform -> SGPRs

  auto loadx = [&](float4* dst) {
    dst[0] = *(const float4*)(px - (size_t)DIL * 4);
    dst[1] = *(const float4*)px;
    dst[2] = *(const float4*)(px + (size_t)DIL * 4);
    px += (size_t)XS * 4;
  };
  auto loadw = [&](int ci, float (*w)[8]) {
#pragma unroll
    for (int k = 0; k < 3; ++k)
#pragma unroll
      for (int j = 0; j < 8; ++j)
        w[k][j] = cw[(ci * 3 + k) * 8 + j];  // s_load (merged)
  };
  auto compute = [&](const float (*w)[8], const float4* xv) {
#pragma unroll
    for (int k = 0; k < 3; ++k) {
      const v2f* xp = (const v2f*)&xv[k];  // {t0,t1}, {t2,t3}
      v2f x0 = xp[0], x1 = xp[1];
#pragma unroll
      for (int j = 0; j < 8; ++j) {
        float wv = w[k][j];
        acc2[j][0] += wv * x0;  // v_pk_fma_f32 acc, s_w(bcast), v_x
        acc2[j][1] += wv * x1;
      }
    }
  };

  loadx(xa);
  loadw(0, wA);
  for (int ci = 0; ci < 64; ci += 2) {
    loadx(xb);
    loadw(ci + 1, wB);
    compute(wA, xa);
    if (ci + 2 < 64) {
      loadx(xa);
      loadw(ci + 2, wA);
    }
    compute(wB, xb);
  }

  const float SIG1 = 0.73105857863000489f;   // sigmoid(1) fp32
  const float TANH1 = 0.76159415595576486f;  // tanh(1) fp32
  bool lb = (l < DIL), rb = (l >= LL - DIL);
#pragma unroll
  for (int j = 0; j < 4; ++j) {
    int cog = g * 4 + j;
    int cof = 64 + g * 4 + j;
    const float* pg = pc + ((layer * 4 + b) * 128 + cog) * 3;
    const float* pf = pc + ((layer * 4 + b) * 128 + cof) * 3;
    float S0g = pg[0], S1g = pg[1], S2g = pg[2];
    float S0f = pf[0], S1f = pf[1], S2f = pf[2];
    float bg = conv_b[layer * 128 + cog] + S0g + S1g + S2g;
    float bf = conv_b[layer * 128 + cof] + S0f + S1f + S2f;
    bg -= (lb ? S0g : 0.0f) + (rb ? S2g : 0.0f);
    bf -= (lb ? S0f : 0.0f) + (rb ? S2f : 0.0f);
    float vg = 0.0f, vf = 0.0f;
    float4 o;
    float* op = (float*)&o;
#pragma unroll
    for (int t = 0; t < 4; ++t) {
      float av = acc2[j][t >> 1][t & 1];
      float fv = acc2[j + 4][t >> 1][t & 1];
      float sg = lif_step(vg, av + bg);
      float sf = lif_step(vf, fv + bf);
      float gv = (sg != 0.0f) ? SIG1 : 0.5f;
      float tv = (sf != 0.0f) ? TANH1 : 0.0f;
      op[t] = gv * tv;
    }
    *(float4*)&y[(size_t)((b * 64 + cog) * LL + l) * 4] = o;
  }
}

// ---------------- 1x1 skip + res convs, MERGED (proven R9/R10/R12) ------------
// grid (128, 4): l-tile 32, b. block 256. One block computes BOTH skip and
// res for its tile -> y tile read ONCE. Thread: 4 c x 2 l x 4 t x
// {skip,res} (32 v2f acc). Per cp: skip-w float4 + res-w float4 + 2 y
// float4, prefetched 1 cp ahead. cp ascending -> bit-exact.
__global__ __launch_bounds__(256) void skip_res_kernel(
    const float* __restrict__ y, const float* __restrict__ skipT,
    const float* __restrict__ resT, const float* __restrict__ skip_b,
    const float* __restrict__ res_b, float* __restrict__ tskip,
    float* __restrict__ x, int layer) {
  int tid = threadIdx.x;
  int lg = tid & 15;   // 16 l-groups of 2
  int cg = tid >> 4;   // 16 c-groups of 4
  int b = blockIdx.y;
  int l0 = blockIdx.x * 32 + lg * 2;
  int c0 = cg * 4;

  const float* ws_ = skipT + layer * 4096 + c0;  // [cp][c]
  const float* wr_ = resT + layer * 4096 + c0;
  const float* yb = y + (size_t)(b * 64 * LL + l0) * 4;

  v2f as_[16], ar_[16];  // [c4][l2][t-pair2]
#pragma unroll
  for (int q = 0; q < 16; ++q) {
    as_[q] = (v2f)(0.0f);
    ar_[q] = (v2f)(0.0f);
  }

  float4 wsa = *(const float4*)&ws_[0];
  float4 wra = *(const float4*)&wr_[0];
  float4 y0a = *(const float4*)yb;             // l0, t0..3
  float4 y1a = *(const float4*)(yb + 4);       // l0+1, t0..3

  for (int cp = 0; cp < 64; ++cp) {
    int cpn = (cp < 63) ? cp + 1 : 63;
    float4 wsb = *(const float4*)&ws_[cpn * 64];
    float4 wrb = *(const float4*)&wr_[cpn * 64];
    float4 y0b = *(const float4*)(yb + (size_t)cpn * LL * 4);
    float4 y1b = *(const float4*)(yb + (size_t)cpn * LL * 4 + 4);

    float wsv[4] = {wsa.x, wsa.y, wsa.z, wsa.w};
    float wrv[4] = {wra.x, wra.y, wra.z, wra.w};
    const v2f* yp0 = (const v2f*)&y0a;  // t01, t23
    const v2f* yp1 = (const v2f*)&y1a;
#pragma unroll
    for (int i = 0; i < 4; ++i) {
      v2f w2s, w2r;
      w2s.x = wsv[i]; w2s.y = wsv[i];
      w2r.x = wrv[i]; w2r.y = wrv[i];
      as_[i * 4 + 0] += w2s * yp0[0];
      as_[i * 4 + 1] += w2s * yp0[1];
      as_[i * 4 + 2] += w2s * yp1[0];
      as_[i * 4 + 3] += w2s * yp1[1];
      ar_[i * 4 + 0] += w2r * yp0[0];
      ar_[i * 4 + 1] += w2r * yp0[1];
      ar_[i * 4 + 2] += w2r * yp1[0];
      ar_[i * 4 + 3] += w2r * yp1[1];
    }
    wsa = wsb; wra = wrb; y0a = y0b; y1a = y1b;
  }

#pragma unroll
  for (int i = 0; i < 4; ++i) {
    int c = c0 + i;
    float sb = skip_b[layer * 64 + c];
    float rb = res_b[layer * 64 + c];
    // skip -> tskip RMW (l0, l0+1)
    {
      size_t idx = (size_t)((b * 64 + c) * LL + l0) * 4;
      float4 o0, o1;
      if (layer == 0) {
        o0 = float4{0.f, 0.f, 0.f, 0.f};
        o1 = o0;
      } else {
        o0 = *(const float4*)&tskip[idx];
        o1 = *(const float4*)&tskip[idx + 4];
      }
      o0.x += as_[i * 4 + 0][0] + sb;
      o0.y += as_[i * 4 + 0][1] + sb;
      o0.z += as_[i * 4 + 1][0] + sb;
      o0.w += as_[i * 4 + 1][1] + sb;
      o1.x += as_[i * 4 + 2][0] + sb;
      o1.y += as_[i * 4 + 2][1] + sb;
      o1.z += as_[i * 4 + 3][0] + sb;
      o1.w += as_[i * 4 + 3][1] + sb;
      *(float4*)&tskip[idx] = o0;
      *(float4*)&tskip[idx + 4] = o1;
    }
    // res -> x RMW (l0, l0+1)
    {
      size_t idx = (size_t)((b * 64 + c) * XS + XPAD + l0) * 4;
      float4 o0 = *(const float4*)&x[idx];
      float4 o1 = *(const float4*)&x[idx + 4];
      o0.x += ar_[i * 4 + 0][0] + rb;
      o0.y += ar_[i * 4 + 0][1] + rb;
      o0.z += ar_[i * 4 + 1][0] + rb;
      o0.w += ar_[i * 4 + 1][1] + rb;
      o1.x += ar_[i * 4 + 2][0] + rb;
      o1.y += ar_[i * 4 + 2][1] + rb;
      o1.z += ar_[i * 4 + 3][0] + rb;
      o1.w += ar_[i * 4 + 3][1] + rb;
      *(float4*)&x[idx] = o0;
      *(float4*)&x[idx + 4] = o1;
    }
  }
}

// ---------------- output conv + LIF + sum over T ----------------
__global__ void out_kernel(const float* __restrict__ tskip,
                           const float* __restrict__ W_out,
                           const float* __restrict__ b_out,
                           float* __restrict__ out) {
  __shared__ float red[4][4][64];  // [grp][t][lq]
  int tid = threadIdx.x;
  int lq = tid & 63, grp = tid >> 6;
  int l = blockIdx.x * 64 + lq;
  int b = blockIdx.y;
  float acc[4] = {0.0f, 0.0f, 0.0f, 0.0f};
  for (int j = 0; j < 16; ++j) {
    int c = grp * 16 + j;
    float w = W_out[c];
    float4 sv = *(const float4*)&tskip[(size_t)((b * 64 + c) * LL + l) * 4];
    acc[0] += fmaxf(sv.x, 0.0f) * w;
    acc[1] += fmaxf(sv.y, 0.0f) * w;
    acc[2] += fmaxf(sv.z, 0.0f) * w;
    acc[3] += fmaxf(sv.w, 0.0f) * w;
  }
#pragma unroll
  for (int t = 0; t < 4; ++t) red[grp][t][lq] = acc[t];
  __syncthreads();
  if (grp == 0) {
    float bo = b_out[0];
    float v = 0.0f, s = 0.0f;
#pragma unroll
    for (int t = 0; t < 4; ++t) {
      float a = red[0][t][lq] + red[1][t][lq] + red[2][t][lq] + red[3][t][lq] + bo;
      s += lif_step(v, a);
    }
    out[b * LL + l] = s;
  }
}

extern "C" void kernel_launch(void* const* d_in, const int* in_sizes, int n_in,
                              void* d_out, int out_size, void* d_ws, size_t ws_size,
                              hipStream_t stream) {
  const float* audio   = (const float*)d_in[0];
  const int*   dstep   = (const int*)d_in[1];
  const float* W_in    = (const float*)d_in[2];
  const float* b_in    = (const float*)d_in[3];
  const float* demb_w1 = (const float*)d_in[4];
  const float* demb_b1 = (const float*)d_in[5];
  const float* demb_w2 = (const float*)d_in[6];
  const float* demb_b2 = (const float*)d_in[7];
  const float* dproj_w = (const float*)d_in[8];
  const float* dproj_b = (const float*)d_in[9];
  const float* conv_w  = (const float*)d_in[10];
  const float* conv_b  = (const float*)d_in[11];
  const float* skip_w  = (const float*)d_in[12];
  const float* skip_b  = (const float*)d_in[13];
  const float* res_w   = (const float*)d_in[14];
  const float* res_b   = (const float*)d_in[15];
  const float* W_out   = (const float*)d_in[16];
  const float* b_out   = (const float*)d_in[17];
  float* out = (float*)d_out;
  float* ws = (float*)d_ws;

  float* proj  = ws;                   // 2560
  float* skipT = proj + 2560;          // 40960
  float* resT  = skipT + 40960;        // 40960
  float* pc    = resT + 40960;         // 15360
  float* wT    = pc + 15360;           // 10*16*64*24 = 245760
  float* x     = wT + 245760;          // 4*64*5120*4 = 5242880
  float* y     = x + 5242880;          // 4*64*4096*4 = 4194304
  float* tskip = y + 4194304;          // 4194304

  prep_kernel<<<dim3(10, 8), 256, 0, stream>>>(skip_w, res_w, conv_w, skipT,
                                               resT, wT);
  proj_kernel<<<10, 256, 0, stream>>>(dstep, demb_w1, demb_b1, demb_w2, demb_b2,
                                      dproj_w, dproj_b, proj);
  pc_kernel<<<dim3(10, 4), 128, 0, stream>>>(proj, conv_w, pc);
  encode_lif_kernel<<<dim3(64, 4), 256, 0, stream>>>(audio, W_in, b_in, x);

  for (int i = 0; i < NLAYERS; ++i) {
    dim3 gc(16, 16, 4);
    switch (i) {
      case 0: layer_conv_kernel<1><<<gc, 256, 0, stream>>>(x, wT, conv_b, pc, y, i); break;
      case 1: layer_conv_kernel<2><<<gc, 256, 0, stream>>>(x, wT, conv_b, pc, y, i); break;
      case 2: layer_conv_kernel<4><<<gc, 256, 0, stream>>>(x, wT, conv_b, pc, y, i); break;
      case 3: layer_conv_kernel<8><<<gc, 256, 0, stream>>>(x, wT, conv_b, pc, y, i); break;
      case 4: layer_conv_kernel<16><<<gc, 256, 0, stream>>>(x, wT, conv_b, pc, y, i); break;
      case 5: layer_conv_kernel<32><<<gc, 256, 0, stream>>>(x, wT, conv_b, pc, y, i); break;
      case 6: layer_conv_kernel<64><<<gc, 256, 0, stream>>>(x, wT, conv_b, pc, y, i); break;
      case 7: layer_conv_kernel<128><<<gc, 256, 0, stream>>>(x, wT, conv_b, pc, y, i); break;
      case 8: layer_conv_kernel<256><<<gc, 256, 0, stream>>>(x, wT, conv_b, pc, y, i); break;
      case 9: layer_conv_kernel<512><<<gc, 256, 0, stream>>>(x, wT, conv_b, pc, y, i); break;
    }
    skip_res_kernel<<<dim3(128, 4), 256, 0, stream>>>(y, skipT, resT, skip_b,
                                                      res_b, tskip, x, i);
  }
  out_kernel<<<dim3(64, 4), 256, 0, stream>>>(tskip, W_out, b_out, out);
}

// Round 14
// 748.909 us; speedup vs baseline: 1.1493x; 1.0211x over previous
//
#include <hip/hip_runtime.h>

#define LL 4096
#define NB 4
#define NC 64
#define NT 4
#define NLAYERS 10
#define XS 5120   // padded x row stride (in l units; x is [B][C][XS][4])
#define XPAD 512  // left/right zero pad (>= max dilation)

typedef float v2f __attribute__((ext_vector_type(2)));

// Constant-address-space cast: forces s_load for wave-uniform weight reads ->
// weights live in SGPRs (proven R6: 47.4us).
typedef __attribute__((address_space(4))) const float cfloat;
typedef __attribute__((address_space(4))) const double cdouble;
__device__ __forceinline__ cfloat* to_constant(const float* p) {
  return (cfloat*)(unsigned long long)p;
}

// ---------------- Threefry-2x32, key = (0, 42), 20 rounds ----------------
__device__ __forceinline__ void threefry2x32(unsigned x0, unsigned x1,
                                             unsigned& o0, unsigned& o1) {
  const unsigned ks0 = 0u, ks1 = 42u;
  const unsigned ks2 = 0x1BD11BDAu ^ ks0 ^ ks1;
  const unsigned ks[3] = {ks0, ks1, ks2};
  const unsigned r0[4] = {13u, 15u, 26u, 6u};
  const unsigned r1[4] = {17u, 29u, 16u, 24u};
  x0 += ks0; x1 += ks1;
#pragma unroll
  for (int g = 0; g < 5; ++g) {
    const unsigned* rr = (g & 1) ? r1 : r0;
#pragma unroll
    for (int j = 0; j < 4; ++j) {
      x0 += x1;
      unsigned r = rr[j];
      x1 = (x1 << r) | (x1 >> (32u - r));
      x1 ^= x0;
    }
    x0 += ks[(g + 1) % 3];
    x1 += ks[(g + 2) % 3] + (unsigned)(g + 1);
  }
  o0 = x0; o1 = x1;
}

__device__ __forceinline__ float u01(unsigned bits) {
  return __uint_as_float((bits >> 9) | 0x3f800000u) - 1.0f;
}

// LIF step: v = v + (x - v)/1.2 ; spike = v>=0.5 ; v *= (1-spike)
__device__ __forceinline__ float lif_step(float& v, float xt) {
  v = v + (xt - v) / 1.2f;
  float s = (v >= 0.5f) ? 1.0f : 0.0f;
  v = v * (1.0f - s);
  return s;
}

// ---------------- prep: transpose skip/res 1x1 + build wT ----------------
// skipT/resT: [i][c'][c]. wT: [i][g16][ci][k][col8], col<4 gate co=g*4+col,
// col>=4 filt co=64+g*4+col-4. (R6 layout.) (10,8) blocks — proven R12.
__global__ void prep_kernel(const float* __restrict__ skip_w,
                            const float* __restrict__ res_w,
                            const float* __restrict__ conv_w,
                            float* __restrict__ skipT,
                            float* __restrict__ resT,
                            float* __restrict__ wT) {
  int i = blockIdx.x;
  int slice = blockIdx.y;  // 0..7
  for (int idx = slice * 512 + threadIdx.x; idx < (slice + 1) * 512; idx += 256) {
    int c = idx >> 6, cp = idx & 63;
    skipT[i * 4096 + cp * 64 + c] = skip_w[i * 4096 + c * 64 + cp];
    resT[i * 4096 + cp * 64 + c] = res_w[i * 4096 + c * 64 + cp];
  }
  for (int idx = slice * 3072 + threadIdx.x; idx < (slice + 1) * 3072; idx += 256) {
    int col = idx & 7;
    int r = idx >> 3;
    int k = r % 3; r /= 3;
    int ci = r % 64;
    int g = r / 64;  // 0..15
    int co = (col < 4) ? (g * 4 + col) : (64 + g * 4 + (col - 4));
    wT[i * 24576 + idx] = conv_w[(i * 128 + co) * 192 + ci * 3 + k];
  }
}

// ---------------- diffusion-step embedding -> proj[i][b][c] ----------------
__global__ void proj_kernel(const int* __restrict__ dstep,
                            const float* __restrict__ w1, const float* __restrict__ b1,
                            const float* __restrict__ w2, const float* __restrict__ b2,
                            const float* __restrict__ pw, const float* __restrict__ pb,
                            float* __restrict__ proj) {
  __shared__ float e1[NB][NC];
  __shared__ float e2[NB][NC];
  int i = blockIdx.x;
  int tid = threadIdx.x;
  int b = tid >> 6, c = tid & 63;
  float d = (float)dstep[b];
  float v = d * w1[i * 64 + c] + b1[i * 64 + c];
  v = v / (1.0f + expf(-v));  // silu
  e1[b][c] = v;
  __syncthreads();
  float a = b2[i * 64 + c];
  for (int cp = 0; cp < 64; ++cp) a += e1[b][cp] * w2[(i * 64 + c) * 64 + cp];
  e2[b][c] = a;
  __syncthreads();
  float p = pb[i * 64 + c];
  for (int cp = 0; cp < 64; ++cp) p += e2[b][cp] * pw[(i * 64 + c) * 64 + cp];
  proj[(i * 4 + b) * 64 + c] = p;
}

// ---------------- per-(layer,b,co) proj-weighted tap sums S0,S1,S2 ----------------
__global__ void pc_kernel(const float* __restrict__ proj,
                          const float* __restrict__ conv_w,
                          float* __restrict__ pc) {
  __shared__ float pv[64];
  int layer = blockIdx.x, b = blockIdx.y;
  int tid = threadIdx.x;  // 128
  if (tid < 64) pv[tid] = proj[(layer * 4 + b) * 64 + tid];
  __syncthreads();
  int co = tid;
  const float* w = conv_w + (layer * 128 + co) * 192;
  float s0 = 0.0f, s1 = 0.0f, s2 = 0.0f;
  for (int ci = 0; ci < 64; ++ci) {
    float p = pv[ci];
    s0 += p * w[ci * 3 + 0];
    s1 += p * w[ci * 3 + 1];
    s2 += p * w[ci * 3 + 2];
  }
  float* o = pc + ((layer * 4 + b) * 128 + co) * 3;
  o[0] = s0; o[1] = s1; o[2] = s2;
}

// ---------------- Poisson encode + input conv + LIF -> x [B][C][XS][4] ---------
// Pad-zeroing folded in (proven R12): block (lx, b) zeros the pad margins of
// row (b, c=lx). Pads and interior are disjoint; pads stay zero across layers.
__global__ void encode_lif_kernel(const float* __restrict__ audio,
                                  const float* __restrict__ W_in,
                                  const float* __restrict__ b_in,
                                  float* __restrict__ x) {
  int tid = threadIdx.x;
  int lq = tid & 63, grp = tid >> 6;
  int l = blockIdx.x * 64 + lq;
  int b = blockIdx.y;
  // zero pads for row (b, c = blockIdx.x)
  {
    float* base = x + (size_t)((b * 64 + blockIdx.x) * XS) * 4;
    for (int q = tid; q < XPAD; q += 256) {
      *(float4*)&base[q * 4] = float4{0.f, 0.f, 0.f, 0.f};
      *(float4*)&base[(XPAD + LL + q) * 4] = float4{0.f, 0.f, 0.f, 0.f};
    }
  }
  float a = audio[b * LL + l];
  unsigned p0 = (unsigned)(b * LL + l);  // t=0 (o0), t=2 (o1)
  unsigned p1 = 16384u + p0;             // t=1 (o0), t=3 (o1)
  unsigned o00, o01, o10, o11;
  threefry2x32(p0, p0 + 32768u, o00, o01);
  threefry2x32(p1, p1 + 32768u, o10, o11);
  float sp[4];
  sp[0] = (u01(o00) < a) ? 1.0f : 0.0f;
  sp[1] = (u01(o10) < a) ? 1.0f : 0.0f;
  sp[2] = (u01(o01) < a) ? 1.0f : 0.0f;
  sp[3] = (u01(o11) < a) ? 1.0f : 0.0f;
  for (int j = 0; j < 16; ++j) {
    int c = grp * 16 + j;
    float w = W_in[c], bb = b_in[c];
    float v = 0.0f;
    float4 o;
    float* op = (float*)&o;
#pragma unroll
    for (int t = 0; t < 4; ++t) op[t] = lif_step(v, w * sp[t] + bb);
    *(float4*)&x[(size_t)((b * 64 + c) * XS + XPAD + l) * 4] = o;
  }
}

// ---------------- dilated conv + LIF + gate -> y [B][64][LL][4] ----------------
// R6 structure (SGPR weights, wA/wB 1-ci double buffer, x float4 1-ci
// double buffer — proven 47.4-48.9us) with ONE change: the MAC is forced to
// v_pk_fma_f32 via inline asm. Weights are loaded as DOUBLE pairs (two
// adjacent co weights per SGPR pair — contiguous in wT, s_load_dwordx2, no
// repacking). VOP3P op_sel broadcasts either word of the SGPR pair to both
// result halves:
//   even co: op_sel:[0,0,0] op_sel_hi:[0,1,1]  (both halves use word0)
//   odd  co: op_sel:[1,0,0] op_sel_hi:[1,1,1]  (both halves use word1)
// x is the natural {t0,t1}/{t2,t3} VGPR pair. Per (ci,k): 16 pk_fma, zero
// movs/packs, vs 32 v_fmac (R12/R13 — R13's C-level v2f was scalarized by
// the compiler: VALUBusy*dur unchanged). FMA issue halves: 12.3K -> 6.1K
// cyc/wave. fma semantics + (ci asc, k asc) order unchanged -> bit-exact.
template <int DIL>
__global__ __launch_bounds__(256) void layer_conv_kernel(
    const float* __restrict__ x, const float* __restrict__ wT,
    const float* __restrict__ conv_b, const float* __restrict__ pc,
    float* __restrict__ y, int layer) {
  int tid = threadIdx.x;
  int g = blockIdx.y;   // 0..15
  int b = blockIdx.z;
  int l = blockIdx.x * 256 + tid;
  cfloat* cw = to_constant(wT + (size_t)(layer * 16 + g) * 1536);

  const float* px = x + (size_t)(b * 64 * XS + XPAD + l) * 4;  // ci=0 row

  v2f acc2[8][2];  // [col][t-pair]; col 0-3 gate, 4-7 filt
#pragma unroll
  for (int j = 0; j < 8; ++j) {
    acc2[j][0] = (v2f)(0.0f);
    acc2[j][1] = (v2f)(0.0f);
  }

  float4 xa[3], xb[3];        // [k] = 4 t values
  double wA[3][4], wB[3][4];  // [k][col-pair] wave-uniform -> SGPR pairs

  auto loadx = [&](float4* dst) {
    dst[0] = *(const float4*)(px - (size_t)DIL * 4);
    dst[1] = *(const float4*)px;
    dst[2] = *(const float4*)(px + (size_t)DIL * 4);
    px += (size_t)XS * 4;
  };
  auto loadw = [&](int ci, double (*w)[4]) {
#pragma unroll
    for (int k = 0; k < 3; ++k) {
      cdouble* p = (cdouble*)(cw + (ci * 3 + k) * 8);
#pragma unroll
      for (int j = 0; j < 4; ++j) w[k][j] = p[j];  // s_load pairs (merged)
    }
  };
  auto compute = [&](const double (*w)[4], const float4* xv) {
#pragma unroll
    for (int k = 0; k < 3; ++k) {
      const v2f* xp = (const v2f*)&xv[k];  // {t0,t1}, {t2,t3}
#pragma unroll
      for (int p = 0; p < 2; ++p) {
        v2f xq = xp[p];
#pragma unroll
        for (int j4 = 0; j4 < 4; ++j4) {
          asm("v_pk_fma_f32 %0, %1, %2, %0 op_sel:[0,0,0] op_sel_hi:[0,1,1]"
              : "+v"(acc2[j4 * 2 + 0][p])
              : "s"(w[k][j4]), "v"(xq));
          asm("v_pk_fma_f32 %0, %1, %2, %0 op_sel:[1,0,0] op_sel_hi:[1,1,1]"
              : "+v"(acc2[j4 * 2 + 1][p])
              : "s"(w[k][j4]), "v"(xq));
        }
      }
    }
  };

  loadx(xa);
  loadw(0, wA);
  for (int ci = 0; ci < 64; ci += 2) {
    loadx(xb);
    loadw(ci + 1, wB);
    compute(wA, xa);
    if (ci + 2 < 64) {
      loadx(xa);
      loadw(ci + 2, wA);
    }
    compute(wB, xb);
  }

  const float SIG1 = 0.73105857863000489f;   // sigmoid(1) fp32
  const float TANH1 = 0.76159415595576486f;  // tanh(1) fp32
  bool lb = (l < DIL), rb = (l >= LL - DIL);
#pragma unroll
  for (int j = 0; j < 4; ++j) {
    int cog = g * 4 + j;
    int cof = 64 + g * 4 + j;
    const float* pg = pc + ((layer * 4 + b) * 128 + cog) * 3;
    const float* pf = pc + ((layer * 4 + b) * 128 + cof) * 3;
    float S0g = pg[0], S1g = pg[1], S2g = pg[2];
    float S0f = pf[0], S1f = pf[1], S2f = pf[2];
    float bg = conv_b[layer * 128 + cog] + S0g + S1g + S2g;
    float bf = conv_b[layer * 128 + cof] + S0f + S1f + S2f;
    bg -= (lb ? S0g : 0.0f) + (rb ? S2g : 0.0f);
    bf -= (lb ? S0f : 0.0f) + (rb ? S2f : 0.0f);
    float vg = 0.0f, vf = 0.0f;
    float4 o;
    float* op = (float*)&o;
#pragma unroll
    for (int t = 0; t < 4; ++t) {
      float av = acc2[j][t >> 1][t & 1];
      float fv = acc2[j + 4][t >> 1][t & 1];
      float sg = lif_step(vg, av + bg);
      float sf = lif_step(vf, fv + bf);
      float gv = (sg != 0.0f) ? SIG1 : 0.5f;
      float tv = (sf != 0.0f) ? TANH1 : 0.0f;
      op[t] = gv * tv;
    }
    *(float4*)&y[(size_t)((b * 64 + cog) * LL + l) * 4] = o;
  }
}

// ---------------- 1x1 skip + res convs, MERGED (proven R9/R10/R12) ------------
// grid (128, 4): l-tile 32, b. block 256. One block computes BOTH skip and
// res for its tile -> y tile read ONCE. Thread: 4 c x 2 l x 4 t x
// {skip,res} (32 v2f acc). Per cp: skip-w float4 + res-w float4 + 2 y
// float4, prefetched 1 cp ahead. cp ascending -> bit-exact.
__global__ __launch_bounds__(256) void skip_res_kernel(
    const float* __restrict__ y, const float* __restrict__ skipT,
    const float* __restrict__ resT, const float* __restrict__ skip_b,
    const float* __restrict__ res_b, float* __restrict__ tskip,
    float* __restrict__ x, int layer) {
  int tid = threadIdx.x;
  int lg = tid & 15;   // 16 l-groups of 2
  int cg = tid >> 4;   // 16 c-groups of 4
  int b = blockIdx.y;
  int l0 = blockIdx.x * 32 + lg * 2;
  int c0 = cg * 4;

  const float* ws_ = skipT + layer * 4096 + c0;  // [cp][c]
  const float* wr_ = resT + layer * 4096 + c0;
  const float* yb = y + (size_t)(b * 64 * LL + l0) * 4;

  v2f as_[16], ar_[16];  // [c4][l2][t-pair2]
#pragma unroll
  for (int q = 0; q < 16; ++q) {
    as_[q] = (v2f)(0.0f);
    ar_[q] = (v2f)(0.0f);
  }

  float4 wsa = *(const float4*)&ws_[0];
  float4 wra = *(const float4*)&wr_[0];
  float4 y0a = *(const float4*)yb;             // l0, t0..3
  float4 y1a = *(const float4*)(yb + 4);       // l0+1, t0..3

  for (int cp = 0; cp < 64; ++cp) {
    int cpn = (cp < 63) ? cp + 1 : 63;
    float4 wsb = *(const float4*)&ws_[cpn * 64];
    float4 wrb = *(const float4*)&wr_[cpn * 64];
    float4 y0b = *(const float4*)(yb + (size_t)cpn * LL * 4);
    float4 y1b = *(const float4*)(yb + (size_t)cpn * LL * 4 + 4);

    float wsv[4] = {wsa.x, wsa.y, wsa.z, wsa.w};
    float wrv[4] = {wra.x, wra.y, wra.z, wra.w};
    const v2f* yp0 = (const v2f*)&y0a;  // t01, t23
    const v2f* yp1 = (const v2f*)&y1a;
#pragma unroll
    for (int i = 0; i < 4; ++i) {
      v2f w2s, w2r;
      w2s.x = wsv[i]; w2s.y = wsv[i];
      w2r.x = wrv[i]; w2r.y = wrv[i];
      as_[i * 4 + 0] += w2s * yp0[0];
      as_[i * 4 + 1] += w2s * yp0[1];
      as_[i * 4 + 2] += w2s * yp1[0];
      as_[i * 4 + 3] += w2s * yp1[1];
      ar_[i * 4 + 0] += w2r * yp0[0];
      ar_[i * 4 + 1] += w2r * yp0[1];
      ar_[i * 4 + 2] += w2r * yp1[0];
      ar_[i * 4 + 3] += w2r * yp1[1];
    }
    wsa = wsb; wra = wrb; y0a = y0b; y1a = y1b;
  }

#pragma unroll
  for (int i = 0; i < 4; ++i) {
    int c = c0 + i;
    float sb = skip_b[layer * 64 + c];
    float rb = res_b[layer * 64 + c];
    // skip -> tskip RMW (l0, l0+1)
    {
      size_t idx = (size_t)((b * 64 + c) * LL + l0) * 4;
      float4 o0, o1;
      if (layer == 0) {
        o0 = float4{0.f, 0.f, 0.f, 0.f};
        o1 = o0;
      } else {
        o0 = *(const float4*)&tskip[idx];
        o1 = *(const float4*)&tskip[idx + 4];
      }
      o0.x += as_[i * 4 + 0][0] + sb;
      o0.y += as_[i * 4 + 0][1] + sb;
      o0.z += as_[i * 4 + 1][0] + sb;
      o0.w += as_[i * 4 + 1][1] + sb;
      o1.x += as_[i * 4 + 2][0] + sb;
      o1.y += as_[i * 4 + 2][1] + sb;
      o1.z += as_[i * 4 + 3][0] + sb;
      o1.w += as_[i * 4 + 3][1] + sb;
      *(float4*)&tskip[idx] = o0;
      *(float4*)&tskip[idx + 4] = o1;
    }
    // res -> x RMW (l0, l0+1)
    {
      size_t idx = (size_t)((b * 64 + c) * XS + XPAD + l0) * 4;
      float4 o0 = *(const float4*)&x[idx];
      float4 o1 = *(const float4*)&x[idx + 4];
      o0.x += ar_[i * 4 + 0][0] + rb;
      o0.y += ar_[i * 4 + 0][1] + rb;
      o0.z += ar_[i * 4 + 1][0] + rb;
      o0.w += ar_[i * 4 + 1][1] + rb;
      o1.x += ar_[i * 4 + 2][0] + rb;
      o1.y += ar_[i * 4 + 2][1] + rb;
      o1.z += ar_[i * 4 + 3][0] + rb;
      o1.w += ar_[i * 4 + 3][1] + rb;
      *(float4*)&x[idx] = o0;
      *(float4*)&x[idx + 4] = o1;
    }
  }
}

// ---------------- output conv + LIF + sum over T ----------------
__global__ void out_kernel(const float* __restrict__ tskip,
                           const float* __restrict__ W_out,
                           const float* __restrict__ b_out,
                           float* __restrict__ out) {
  __shared__ float red[4][4][64];  // [grp][t][lq]
  int tid = threadIdx.x;
  int lq = tid & 63, grp = tid >> 6;
  int l = blockIdx.x * 64 + lq;
  int b = blockIdx.y;
  float acc[4] = {0.0f, 0.0f, 0.0f, 0.0f};
  for (int j = 0; j < 16; ++j) {
    int c = grp * 16 + j;
    float w = W_out[c];
    float4 sv = *(const float4*)&tskip[(size_t)((b * 64 + c) * LL + l) * 4];
    acc[0] += fmaxf(sv.x, 0.0f) * w;
    acc[1] += fmaxf(sv.y, 0.0f) * w;
    acc[2] += fmaxf(sv.z, 0.0f) * w;
    acc[3] += fmaxf(sv.w, 0.0f) * w;
  }
#pragma unroll
  for (int t = 0; t < 4; ++t) red[grp][t][lq] = acc[t];
  __syncthreads();
  if (grp == 0) {
    float bo = b_out[0];
    float v = 0.0f, s = 0.0f;
#pragma unroll
    for (int t = 0; t < 4; ++t) {
      float a = red[0][t][lq] + red[1][t][lq] + red[2][t][lq] + red[3][t][lq] + bo;
      s += lif_step(v, a);
    }
    out[b * LL + l] = s;
  }
}

extern "C" void kernel_launch(void* const* d_in, const int* in_sizes, int n_in,
                              void* d_out, int out_size, void* d_ws, size_t ws_size,
                              hipStream_t stream) {
  const float* audio   = (const float*)d_in[0];
  const int*   dstep   = (const int*)d_in[1];
  const float* W_in    = (const float*)d_in[2];
  const float* b_in    = (const float*)d_in[3];
  const float* demb_w1 = (const float*)d_in[4];
  const float* demb_b1 = (const float*)d_in[5];
  const float* demb_w2 = (const float*)d_in[6];
  const float* demb_b2 = (const float*)d_in[7];
  const float* dproj_w = (const float*)d_in[8];
  const float* dproj_b = (const float*)d_in[9];
  const float* conv_w  = (const float*)d_in[10];
  const float* conv_b  = (const float*)d_in[11];
  const float* skip_w  = (const float*)d_in[12];
  const float* skip_b  = (const float*)d_in[13];
  const float* res_w   = (const float*)d_in[14];
  const float* res_b   = (const float*)d_in[15];
  const float* W_out   = (const float*)d_in[16];
  const float* b_out   = (const float*)d_in[17];
  float* out = (float*)d_out;
  float* ws = (float*)d_ws;

  float* proj  = ws;                   // 2560
  float* skipT = proj + 2560;          // 40960
  float* resT  = skipT + 40960;        // 40960
  float* pc    = resT + 40960;         // 15360
  float* wT    = pc + 15360;           // 10*16*64*24 = 245760
  float* x     = wT + 245760;          // 4*64*5120*4 = 5242880
  float* y     = x + 5242880;          // 4*64*4096*4 = 4194304
  float* tskip = y + 4194304;          // 4194304

  prep_kernel<<<dim3(10, 8), 256, 0, stream>>>(skip_w, res_w, conv_w, skipT,
                                               resT, wT);
  proj_kernel<<<10, 256, 0, stream>>>(dstep, demb_w1, demb_b1, demb_w2, demb_b2,
                                      dproj_w, dproj_b, proj);
  pc_kernel<<<dim3(10, 4), 128, 0, stream>>>(proj, conv_w, pc);
  encode_lif_kernel<<<dim3(64, 4), 256, 0, stream>>>(audio, W_in, b_in, x);

  for (int i = 0; i < NLAYERS; ++i) {
    dim3 gc(16, 16, 4);
    switch (i) {
      case 0: layer_conv_kernel<1><<<gc, 256, 0, stream>>>(x, wT, conv_b, pc, y, i); break;
      case 1: layer_conv_kernel<2><<<gc, 256, 0, stream>>>(x, wT, conv_b, pc, y, i); break;
      case 2: layer_conv_kernel<4><<<gc, 256, 0, stream>>>(x, wT, conv_b, pc, y, i); break;
      case 3: layer_conv_kernel<8><<<gc, 256, 0, stream>>>(x, wT, conv_b, pc, y, i); break;
      case 4: layer_conv_kernel<16><<<gc, 256, 0, stream>>>(x, wT, conv_b, pc, y, i); break;
      case 5: layer_conv_kernel<32><<<gc, 256, 0, stream>>>(x, wT, conv_b, pc, y, i); break;
      case 6: layer_conv_kernel<64><<<gc, 256, 0, stream>>>(x, wT, conv_b, pc, y, i); break;
      case 7: layer_conv_kernel<128><<<gc, 256, 0, stream>>>(x, wT, conv_b, pc, y, i); break;
      case 8: layer_conv_kernel<256><<<gc, 256, 0, stream>>>(x, wT, conv_b, pc, y, i); break;
      case 9: layer_conv_kernel<512><<<gc, 256, 0, stream>>>(x, wT, conv_b, pc, y, i); break;
    }
    skip_res_kernel<<<dim3(128, 4), 256, 0, stream>>>(y, skipT, resT, skip_b,
                                                      res_b, tskip, x, i);
  }
  out_kernel<<<dim3(64, 4), 256, 0, stream>>>(tskip, W_out, b_out, out);
}